// Round 5
// baseline (70.360 us; speedup 1.0000x reference)
//
#include <hip/hip_runtime.h>

// one_layer_net: 130-step scan over a 9x3 LUT-triangle network.
// V6: V5 + K table moved from LDS to global workspace. With one serial wave,
// LDS ops drain through a single in-order pipe (~60 cy/round for 4 bperm +
// 3 ds_read_b128); only the state gathers NEED the LDS crossbar. K rows are
// state-independent -> fetch them on the VMEM pipe (global, L2-resident,
// 6-round prefetch pipeline) so the LDS pipe carries only the 4 bperms
// (~24 cy/round). Bit-exact vs V2/V4/V5: identical fma sequences.
//
//   E(k, x, y) = fma(y, fma(x,k.x,k.y), fma(x,k.z,k.w))
// Round r (steps 2r, 2r+1) for lane l, with a0=A(l), b0=B(l):
//   u1 = E(K[2r][a0], s[A(a0)], s[B(a0)])
//   u2 = E(K[2r][b0], s[A(b0)], s[B(b0)])
//   s' = E(K[2r+1][l], u1, u2)

#define STEPS 130
#define NLUT  27   // 9 triangles x 3 LUTs
#define ROUNDS 65  // 65*2 = 130, no tail
#define PF     6   // K prefetch depth in rounds (covers ~200cy L2 latency)

// Source wiring (indices into flat[29] = [prev.flatten(27), a, b])
__device__ __constant__ int c_idx0[9] = {3, 0, 6, 12, 9, 15, 18, 6, 15};
__device__ __constant__ int c_idx1[9] = {1, 7, 4, 19, 16, 13, 10, 22, 25};
__device__ __constant__ int c_idx2[9] = {17, 5, 11, 8, 28, 2, 27, 23, 26};

// wiring helpers: A(m)/B(m) = gather sources of lane m's update.
// B >= 27 (network inputs a,b) is folded into K0/K1 of row m in phase 1
// (K2=K3=0), so the gather source is a don't-care -> clamp to lane 0.
__device__ __forceinline__ int wA(int m) {
    int t = m / 3, j = m % 3;
    return (j == 0) ? c_idx1[t] : c_idx0[t];
}
__device__ __forceinline__ int wB(int m) {
    int t = m / 3, j = m % 3;
    int s = (j == 2) ? c_idx1[t] : c_idx2[t];
    return (s >= NLUT) ? 0 : s;
}

__device__ __forceinline__ float evalE(float4 k, float x, float y) {
    return fmaf(y, fmaf(x, k.x, k.y), fmaf(x, k.z, k.w));
}

__device__ __forceinline__ float bperm(int byteIdx, float v) {
    return __int_as_float(__builtin_amdgcn_ds_bpermute(byteIdx, __float_as_int(v)));
}

__global__ __launch_bounds__(512)
void one_layer_net_kernel(const float* __restrict__ x,
                          const float* __restrict__ weights,
                          const float* __restrict__ noise,
                          float* __restrict__ out,
                          float4* __restrict__ gK) {
    const int tid = threadIdx.x;
    const float a = x[0];
    const float b = x[1];

    // ---- Phase 1: parallel precompute of K-form coefficients -> GLOBAL ----
    // w' = w + |1 - |w|| * n * 0.125
    // E coefficients: K3=0.25*((w3-w2)-(w1-w0)), K2=0.25*((w2+w3)-(w0+w1)),
    //                 K1=0.25*((w1-w0)+(w3-w2)), K0=0.25*(w0+w1+w2+w3)
    const float4* __restrict__ w4 = (const float4*)weights; // [27]
    const float4* __restrict__ n4 = (const float4*)noise;   // [130*27]
    for (int i = tid; i < STEPS * NLUT; i += 512) {
        const int l = i % NLUT;
        float4 w = w4[l];
        float4 n = n4[i];
        float w0 = fmaf(fabsf(1.0f - fabsf(w.x)) * n.x, 0.125f, w.x);
        float w1 = fmaf(fabsf(1.0f - fabsf(w.y)) * n.y, 0.125f, w.y);
        float w2 = fmaf(fabsf(1.0f - fabsf(w.z)) * n.z, 0.125f, w.z);
        float w3 = fmaf(fabsf(1.0f - fabsf(w.w)) * n.w, 0.125f, w.w);
        float d0 = w1 - w0, s0 = w0 + w1;
        float d1 = w3 - w2, s1 = w2 + w3;
        float K3 = 0.25f * (d1 - d0);
        float K2 = 0.25f * (s1 - s0);
        float K1 = 0.25f * (d0 + d1);
        float K0 = 0.25f * (s0 + s1);
        // fold constant gB inputs: lanes 12,13 read b (flat[28]); 18,19 read a (flat[27])
        if (l == 12 || l == 13) {
            K0 = fmaf(K2, b, K0); K1 = fmaf(K3, b, K1); K2 = 0.0f; K3 = 0.0f;
        }
        if (l == 18 || l == 19) {
            K0 = fmaf(K2, a, K0); K1 = fmaf(K3, a, K1); K2 = 0.0f; K3 = 0.0f;
        }
        gK[i] = make_float4(K3, K2, K1, K0);
    }
    // Make phase-1 global stores visible to wave 0 (same block, same CU; gK
    // lines were never read -> no stale L1; fence drains stores to L2).
    __threadfence_block();
    __syncthreads();

    // ---- Phase 2: serial loop on wave 0 only, 2 steps per round ----
    if (tid >= 64) return;

    const int l  = tid;
    const int lc = (l < NLUT) ? l : (NLUT - 1); // lanes 27..63 mirror lane 26

    // 1-level wiring expansion (all compile-time-constant per lane)
    const int a0 = wA(lc), b0 = wB(lc);
    // leaf gather byte-indices for ds_bpermute (4 per round == 2 per step)
    const int g0 = wA(a0) << 2, g1 = wB(a0) << 2;
    const int g2 = wA(b0) << 2, g3 = wB(b0) << 2;

    // K-row base pointers (global); round r adds r*54 float4s (2 steps x 27)
    const float4* __restrict__ pA = gK + 0 * NLUT + a0;
    const float4* __restrict__ pB = gK + 0 * NLUT + b0;
    const float4* __restrict__ pC = gK + 1 * NLUT + lc;

    // K prefetch pipeline, depth PF. Loop is fully unrolled, so every index
    // is compile-time constant -> registers, not scratch (rule #20).
    float4 bufA[PF], bufB[PF], bufC[PF];
    #pragma unroll
    for (int r = 0; r < PF; ++r) {
        const int o = r * 2 * NLUT;
        bufA[r] = pA[o]; bufB[r] = pB[o]; bufC[r] = pC[o];
    }

    // All lanes init -1; lanes >=27 compute lane-26 duplicates (finite, never read).
    float state = -1.0f;

    #pragma unroll
    for (int r = 0; r < ROUNDS; ++r) {
        // 4 parallel gathers FIRST — the only LDS-pipe ops in the loop
        const float q0 = bperm(g0, state);
        const float q1 = bperm(g1, state);
        const float q2 = bperm(g2, state);
        const float q3 = bperm(g3, state);
        // current K rows (loaded PF rounds ago, VMEM pipe, vmcnt-counted)
        const float4 kA = bufA[r % PF];
        const float4 kB = bufB[r % PF];
        const float4 kC = bufC[r % PF];
        // composed evaluation: 9 fmas, depth 4
        const float u1 = evalE(kA, q0, q1);
        const float u2 = evalE(kB, q2, q3);
        state = evalE(kC, u1, u2);
        // refill the consumed slot with round r+PF (VMEM pipe, fully async)
        if (r + PF < ROUNDS) {
            const int o = (r + PF) * 2 * NLUT;
            bufA[r % PF] = pA[o]; bufB[r % PF] = pB[o]; bufC[r % PF] = pC[o];
        }
    }

    // outputs: final[0,1] -> lane 1, final[1,2] -> lane 5, final[7,2] -> lane 23
    if (l == 1)  out[0] = state;
    if (l == 5)  out[1] = state;
    if (l == 23) out[2] = state;
}

extern "C" void kernel_launch(void* const* d_in, const int* in_sizes, int n_in,
                              void* d_out, int out_size, void* d_ws, size_t ws_size,
                              hipStream_t stream) {
    const float* x       = (const float*)d_in[0]; // [2]
    const float* weights = (const float*)d_in[1]; // [9,3,4]
    const float* noise   = (const float*)d_in[2]; // [130,9,3,4]
    float* out  = (float*)d_out;                  // [3] float32
    float4* gK  = (float4*)d_ws;                  // 130*27*16 = 56160 B of workspace
    one_layer_net_kernel<<<1, 512, 0, stream>>>(x, weights, noise, out, gK);
}

// Round 6
// 65.397 us; speedup vs baseline: 1.0759x; 1.0759x over previous
//
#include <hip/hip_runtime.h>

// one_layer_net: 130-step scan over a 9x3 LUT-triangle network.
// V7 = V5 revert (verified best, 64.37 us). V6's global-K experiment showed
// the VMEM path costs +6 us: with one serial wave there is no TLP to hide
// ~200cy L2 latency and in-order vmcnt retirement serializes the K pipeline.
// V5 structure: 2-step composition + one-round-ahead K prefetch in LDS.
// LDS completion (lgkmcnt) is in-order, so issuing NEXT round's 3
// ds_read_b128 BEFORE this round's 4 ds_bpermute retires them off the
// critical path. Per-round dependent chain: state -> bperm(L) -> 4-deep fma.
// Bit-exact vs V2/V4: identical fma sequences.
//
//   E(k, x, y) = fma(y, fma(x,k.x,k.y), fma(x,k.z,k.w))
// Round r (steps 2r, 2r+1) for lane l, with a0=A(l), b0=B(l):
//   u1 = E(K[2r][a0], s[A(a0)], s[B(a0)])
//   u2 = E(K[2r][b0], s[A(b0)], s[B(b0)])
//   s' = E(K[2r+1][l], u1, u2)

#define STEPS 130
#define NLUT  27   // 9 triangles x 3 LUTs
#define ROUNDS 65  // 65*2 = 130, no tail

// Source wiring (indices into flat[29] = [prev.flatten(27), a, b])
__device__ __constant__ int c_idx0[9] = {3, 0, 6, 12, 9, 15, 18, 6, 15};
__device__ __constant__ int c_idx1[9] = {1, 7, 4, 19, 16, 13, 10, 22, 25};
__device__ __constant__ int c_idx2[9] = {17, 5, 11, 8, 28, 2, 27, 23, 26};

// wiring helpers: A(m)/B(m) = gather sources of lane m's update.
// B >= 27 (network inputs a,b) is folded into K0/K1 of row m in phase 1
// (K2=K3=0), so the gather source is a don't-care -> clamp to lane 0.
__device__ __forceinline__ int wA(int m) {
    int t = m / 3, j = m % 3;
    return (j == 0) ? c_idx1[t] : c_idx0[t];
}
__device__ __forceinline__ int wB(int m) {
    int t = m / 3, j = m % 3;
    int s = (j == 2) ? c_idx1[t] : c_idx2[t];
    return (s >= NLUT) ? 0 : s;
}

__device__ __forceinline__ float evalE(float4 k, float x, float y) {
    return fmaf(y, fmaf(x, k.x, k.y), fmaf(x, k.z, k.w));
}

__device__ __forceinline__ float bperm(int byteIdx, float v) {
    return __int_as_float(__builtin_amdgcn_ds_bpermute(byteIdx, __float_as_int(v)));
}

__global__ __launch_bounds__(1024)
void one_layer_net_kernel(const float* __restrict__ x,
                          const float* __restrict__ weights,
                          const float* __restrict__ noise,
                          float* __restrict__ out) {
    __shared__ float4 tbl[STEPS * NLUT];   // 130*27*16 = 56160 B LDS

    const int tid = threadIdx.x;
    const float a = x[0];
    const float b = x[1];

    // ---- Phase 1: parallel precompute of K-form coefficients ----
    // w' = w + |1 - |w|| * n * 0.125
    // E coefficients: K3=0.25*((w3-w2)-(w1-w0)), K2=0.25*((w2+w3)-(w0+w1)),
    //                 K1=0.25*((w1-w0)+(w3-w2)), K0=0.25*(w0+w1+w2+w3)
    const float4* __restrict__ w4 = (const float4*)weights; // [27]
    const float4* __restrict__ n4 = (const float4*)noise;   // [130*27]
    for (int i = tid; i < STEPS * NLUT; i += 1024) {
        const int l = i % NLUT;
        float4 w = w4[l];
        float4 n = n4[i];
        float w0 = fmaf(fabsf(1.0f - fabsf(w.x)) * n.x, 0.125f, w.x);
        float w1 = fmaf(fabsf(1.0f - fabsf(w.y)) * n.y, 0.125f, w.y);
        float w2 = fmaf(fabsf(1.0f - fabsf(w.z)) * n.z, 0.125f, w.z);
        float w3 = fmaf(fabsf(1.0f - fabsf(w.w)) * n.w, 0.125f, w.w);
        float d0 = w1 - w0, s0 = w0 + w1;
        float d1 = w3 - w2, s1 = w2 + w3;
        float K3 = 0.25f * (d1 - d0);
        float K2 = 0.25f * (s1 - s0);
        float K1 = 0.25f * (d0 + d1);
        float K0 = 0.25f * (s0 + s1);
        // fold constant gB inputs: lanes 12,13 read b (flat[28]); 18,19 read a (flat[27])
        if (l == 12 || l == 13) {
            K0 = fmaf(K2, b, K0); K1 = fmaf(K3, b, K1); K2 = 0.0f; K3 = 0.0f;
        }
        if (l == 18 || l == 19) {
            K0 = fmaf(K2, a, K0); K1 = fmaf(K3, a, K1); K2 = 0.0f; K3 = 0.0f;
        }
        tbl[i] = make_float4(K3, K2, K1, K0);
    }
    __syncthreads();

    // ---- Phase 2: serial loop on wave 0 only, 2 steps per round ----
    if (tid >= 64) return;

    const int l  = tid;
    const int lc = (l < NLUT) ? l : (NLUT - 1); // lanes 27..63 mirror lane 26

    // 1-level wiring expansion (all compile-time-constant per lane)
    const int a0 = wA(lc), b0 = wB(lc);
    // leaf gather byte-indices for ds_bpermute (4 per round == 2 per step)
    const int g0 = wA(a0) << 2, g1 = wB(a0) << 2;
    const int g2 = wA(b0) << 2, g3 = wB(b0) << 2;

    // K-row base pointers; round r adds r*54 float4s (2 steps x 27)
    const float4* __restrict__ pA = tbl + 0 * NLUT + a0;
    const float4* __restrict__ pB = tbl + 0 * NLUT + b0;
    const float4* __restrict__ pC = tbl + 1 * NLUT + lc;

    // All lanes init -1; lanes >=27 compute lane-26 duplicates (finite, never read).
    float state = -1.0f;

    // round-0 K rows loaded up front; thereafter prefetched one round ahead
    float4 kA = pA[0], kB = pB[0], kC = pC[0];

    #pragma unroll
    for (int r = 0; r < ROUNDS; ++r) {
        // Issue NEXT round's K reads FIRST: in-order lgkmcnt retires them
        // before this round's bperms, so they never extend the critical path.
        const int on = ((r + 1 < ROUNDS) ? (r + 1) : r) * 2 * NLUT;
        const float4 kAn = pA[on];
        const float4 kBn = pB[on];
        const float4 kCn = pC[on];
        // 4 parallel gathers — one cross-lane latency epoch for 2 steps
        const float q0 = bperm(g0, state);
        const float q1 = bperm(g1, state);
        const float q2 = bperm(g2, state);
        const float q3 = bperm(g3, state);
        // composed evaluation: 9 fmas, depth 4
        const float u1 = evalE(kA, q0, q1);
        const float u2 = evalE(kB, q2, q3);
        state = evalE(kC, u1, u2);
        kA = kAn; kB = kBn; kC = kCn;
    }

    // outputs: final[0,1] -> lane 1, final[1,2] -> lane 5, final[7,2] -> lane 23
    if (l == 1)  out[0] = state;
    if (l == 5)  out[1] = state;
    if (l == 23) out[2] = state;
}

extern "C" void kernel_launch(void* const* d_in, const int* in_sizes, int n_in,
                              void* d_out, int out_size, void* d_ws, size_t ws_size,
                              hipStream_t stream) {
    const float* x       = (const float*)d_in[0]; // [2]
    const float* weights = (const float*)d_in[1]; // [9,3,4]
    const float* noise   = (const float*)d_in[2]; // [130,9,3,4]
    float* out = (float*)d_out;                   // [3] float32
    one_layer_net_kernel<<<1, 1024, 0, stream>>>(x, weights, noise, out);
}